// Round 4
// baseline (5647.677 us; speedup 1.0000x reference)
//
#include <hip/hip_runtime.h>
#include <hip/hip_bf16.h>
#include <math.h>

#define NN_ 65536
#define NE_ 131072
#define B_  32
#define T_  4096

__device__ __forceinline__ float gelu_f(float x){
    return 0.5f*x*(1.0f + erff(x*0.70710678118654752f));
}

// monotonic float<->uint encoding for atomicMax on floats
__device__ __forceinline__ unsigned enc_f(float f){
    unsigned b = __float_as_uint(f);
    return (b & 0x80000000u) ? ~b : (b | 0x80000000u);
}
__device__ __forceinline__ float dec_f(unsigned u){
    return (u & 0x80000000u) ? __uint_as_float(u ^ 0x80000000u) : __uint_as_float(~u);
}

// broadcast lane l's value of v to all lanes (compile-time l -> v_readlane)
__device__ __forceinline__ float rdlane(float v, int l){
    return __int_as_float(__builtin_amdgcn_readlane(__float_as_int(v), l));
}

// ---------------- zero ----------------
__global__ void k_zero(float* p, int n){
    int i = blockIdx.x*blockDim.x + threadIdx.x;
    int stride = gridDim.x*blockDim.x;
    for(; i<n; i+=stride) p[i] = 0.f;
}

// ---------------- embed concat: h64[n][c] = c<32 ? x[n][c] : emb[nidx[n]][c-32] ----
__global__ void k_embed(const float* __restrict__ x, const int* __restrict__ nidx,
                        const float* __restrict__ emb, float* __restrict__ h64){
    int gid = blockIdx.x*256 + threadIdx.x;
    int n = gid >> 6, c = gid & 63;
    float v = (c < 32) ? x[(size_t)n*32 + c] : emb[(size_t)nidx[n]*32 + (c-32)];
    h64[gid] = v;
}

// ---------------- node GEMM: C[M,128] = A[M,K] @ W[K,128] ----------------
template<int K>
__global__ void k_gemm_node(const float* __restrict__ A, const float* __restrict__ W,
                            float* __restrict__ C){
    int lane = threadIdx.x & 63;
    int wy = threadIdx.x >> 6;
    int r0 = blockIdx.x*16 + wy*4;
    const float* a0 = A + (size_t)r0*K;
    float acc0[4] = {0,0,0,0}, acc1[4] = {0,0,0,0};
    #pragma unroll 4
    for(int k=0;k<K;k+=4){
        float4 av[4];
        #pragma unroll
        for(int i=0;i<4;i++) av[i] = *(const float4*)(a0 + (size_t)i*K + k);
        #pragma unroll
        for(int kk=0;kk<4;kk++){
            float w0 = W[(size_t)(k+kk)*128 + lane];
            float w1 = W[(size_t)(k+kk)*128 + 64 + lane];
            #pragma unroll
            for(int i=0;i<4;i++){
                float a = ((const float*)&av[i])[kk];
                acc0[i] += a*w0;
                acc1[i] += a*w1;
            }
        }
    }
    #pragma unroll
    for(int i=0;i<4;i++){
        C[(size_t)(r0+i)*128 + lane]      = acc0[i];
        C[(size_t)(r0+i)*128 + 64 + lane] = acc1[i];
    }
}

// ---------------- per-row dots: ssrc = hW . a_s, sdst = hW . a_d --------------
__global__ void k_rowdots(const float* __restrict__ hW, const float* __restrict__ as_,
                          const float* __restrict__ ad_, float* __restrict__ ssrc,
                          float* __restrict__ sdst){
    int lane = threadIdx.x & 63;
    int row = blockIdx.x*4 + (threadIdx.x >> 6);
    const float* hp = hW + (size_t)row*128;
    float h0 = hp[lane], h1 = hp[lane+64];
    float d0 = h0*as_[lane] + h1*as_[lane+64];
    float d1 = h0*ad_[lane] + h1*ad_[lane+64];
    #pragma unroll
    for(int off=32; off; off>>=1){
        d0 += __shfl_xor(d0, off);
        d1 += __shfl_xor(d1, off);
    }
    if(lane==0){ ssrc[row] = d0; sdst[row] = d1; }
}

// ---------------- edge pass 1: e = lrelu(ssrc[s]+sdst[d]); max into m[d] ------
__global__ void k_edge1(const int* __restrict__ src, const int* __restrict__ dst,
                        const float* __restrict__ ssrc, const float* __restrict__ sdst,
                        float* __restrict__ ebuf, unsigned* __restrict__ menc){
    int e = blockIdx.x*256 + threadIdx.x;   // e < NE_+NN_
    int s, d;
    if(e < NE_){ s = src[e]; d = dst[e]; } else { s = d = e - NE_; }
    float v = ssrc[s] + sdst[d];
    v = (v > 0.f) ? v : 0.2f*v;
    ebuf[e] = v;
    atomicMax(&menc[d], enc_f(v));
}

// ---------------- edge pass 2: ex = exp(e - m[d]); sum into ssum[d] -----------
__global__ void k_edge2(const int* __restrict__ dst, const unsigned* __restrict__ menc,
                        float* __restrict__ ebuf, float* __restrict__ ssum){
    int e = blockIdx.x*256 + threadIdx.x;
    int d = (e < NE_) ? dst[e] : (e - NE_);
    float m = dec_f(menc[d]);
    float ex = __expf(ebuf[e] - m);
    ebuf[e] = ex;
    atomicAdd(&ssum[d], ex);
}

// ---------------- edge pass 3: hAgg[d] += hW[s] * (ex / ssum[d]) --------------
__global__ void k_edge3(const int* __restrict__ src, const int* __restrict__ dst,
                        const float* __restrict__ ebuf, const float* __restrict__ ssum,
                        const float* __restrict__ hW, float* __restrict__ hAgg){
    int gid = blockIdx.x*256 + threadIdx.x;
    int e = gid >> 5;
    int c = (gid & 31) << 2;
    int s, d;
    if(e < NE_){ s = src[e]; d = dst[e]; } else { s = d = e - NE_; }
    float alpha = ebuf[e] / ssum[d];
    float4 v = *(const float4*)(hW + (size_t)s*128 + c);
    float* o = hAgg + (size_t)d*128 + c;
    atomicAdd(o+0, v.x*alpha);
    atomicAdd(o+1, v.y*alpha);
    atomicAdd(o+2, v.z*alpha);
    atomicAdd(o+3, v.w*alpha);
}

// ---------------- bias + gelu (in place) ----------------
__global__ void k_biasgelu(float* __restrict__ hAgg, const float* __restrict__ bias){
    int gid = blockIdx.x*256 + threadIdx.x;  // NN*128
    int c = gid & 127;
    hAgg[gid] = gelu_f(hAgg[gid] + bias[c]);
}

// ------- fused edge-FC + GRU input projection:
//   efrow = gelu([h3[src[e]] | h3[dst[e]]] @ fcW + fcb)           [128]
//   X3[(t*32+b)*192 + {z|r|h}] = efrow @ {Wz,Wr,Wh}[0:128] + bias [64 each]
__global__ void k_ef_x3(const float* __restrict__ h3, const int* __restrict__ src,
                        const int* __restrict__ dst, const float* __restrict__ fcW,
                        const float* __restrict__ fcb,
                        const float* __restrict__ Wz, const float* __restrict__ Wr,
                        const float* __restrict__ Wh, const float* __restrict__ bz,
                        const float* __restrict__ br, const float* __restrict__ bh,
                        float* __restrict__ X3){
    __shared__ float efs[16][128];
    int lane = threadIdx.x & 63;
    int wy = threadIdx.x >> 6;
    int e0 = blockIdx.x*16 + wy*4;

    // phase 1: edge-FC
    {
        float acc0[4] = {0,0,0,0}, acc1[4] = {0,0,0,0};
        #pragma unroll
        for(int half=0; half<2; half++){
            const float* rowp[4];
            #pragma unroll
            for(int i=0;i<4;i++){
                int n = (half==0) ? src[e0+i] : dst[e0+i];
                rowp[i] = h3 + (size_t)n*128;
            }
            #pragma unroll 2
            for(int k=0;k<128;k+=4){
                float4 av[4];
                #pragma unroll
                for(int i=0;i<4;i++) av[i] = *(const float4*)(rowp[i] + k);
                #pragma unroll
                for(int kk=0;kk<4;kk++){
                    int kw = half*128 + k + kk;
                    float w0 = fcW[(size_t)kw*128 + lane];
                    float w1 = fcW[(size_t)kw*128 + 64 + lane];
                    #pragma unroll
                    for(int i=0;i<4;i++){
                        float a = ((const float*)&av[i])[kk];
                        acc0[i] += a*w0;
                        acc1[i] += a*w1;
                    }
                }
            }
        }
        float b0 = fcb[lane], b1 = fcb[64+lane];
        #pragma unroll
        for(int i=0;i<4;i++){
            efs[wy*4+i][lane]      = gelu_f(acc0[i] + b0);
            efs[wy*4+i][64 + lane] = gelu_f(acc1[i] + b1);
        }
    }
    __syncthreads();
    // phase 2: project to z/r/h inputs
    {
        float accz[4] = {0,0,0,0}, accr[4] = {0,0,0,0}, acch[4] = {0,0,0,0};
        #pragma unroll 2
        for(int k=0;k<128;k+=4){
            #pragma unroll
            for(int kk=0;kk<4;kk++){
                float w0 = Wz[(size_t)(k+kk)*64 + lane];
                float w1 = Wr[(size_t)(k+kk)*64 + lane];
                float w2 = Wh[(size_t)(k+kk)*64 + lane];
                #pragma unroll
                for(int i=0;i<4;i++){
                    float a = efs[wy*4+i][k+kk];
                    accz[i] += a*w0;
                    accr[i] += a*w1;
                    acch[i] += a*w2;
                }
            }
        }
        float b0 = bz[lane], b1 = br[lane], b2 = bh[lane];
        #pragma unroll
        for(int i=0;i<4;i++){
            int e = e0 + i;
            int bb = e >> 12;       // graph
            int t  = e & 4095;      // timestep
            float* o = X3 + ((size_t)t*32 + bb)*192;
            o[lane]       = accz[i] + b0;
            o[64 + lane]  = accr[i] + b1;
            o[128 + lane] = acch[i] + b2;
        }
    }
}

// ---------------- GRU: 1 wave per batch, all-register recurrence --------------
// lane j owns output j. hid distributed 1 elem/lane; broadcasts via v_readlane
// (compile-time lane index), weight columns in VGPRs. No LDS, no barriers.
// __launch_bounds__(64, 1): min 1 wave/EU -> full register budget (no spill of
// the 192-element weight arrays; R3 showed VGPR_Count=108 => spilled weights).
__global__ void __launch_bounds__(64, 1) k_gru(const float* __restrict__ X3,
                       const float* __restrict__ Wz, const float* __restrict__ Wr,
                       const float* __restrict__ Wh, float* __restrict__ out){
    int b = blockIdx.x;
    int j = threadIdx.x;        // 0..63

    // hidden-part weight columns (rows 128..191, col j)
    float wz[64], wr[64], wh[64];
    #pragma unroll
    for(int k=0;k<64;k++){
        wz[k] = Wz[(size_t)(128+k)*64 + j];
        wr[k] = Wr[(size_t)(128+k)*64 + j];
        wh[k] = Wh[(size_t)(128+k)*64 + j];
    }

    float h = 0.f;
    const float* x0 = X3 + (size_t)b*192;
    float xz = x0[j], xr = x0[64+j], xh = x0[128+j];

    for(int step=0; step<T_; step++){
        float nxz, nxr, nxh;
        if(step + 1 < T_){
            const float* np = X3 + ((size_t)(step+1)*32 + b)*192;
            nxz = np[j]; nxr = np[64+j]; nxh = np[128+j];
        } else { nxz = nxr = nxh = 0.f; }

        // z_j, r_j = sigmoid(x + sum_k hid[k] * W[128+k][j])
        float az0 = xz, az1 = 0.f, az2 = 0.f, az3 = 0.f;
        float ar0 = xr, ar1 = 0.f, ar2 = 0.f, ar3 = 0.f;
        #pragma unroll
        for(int k=0;k<64;k+=4){
            float h0 = rdlane(h, k);
            float h1 = rdlane(h, k+1);
            float h2 = rdlane(h, k+2);
            float h3 = rdlane(h, k+3);
            az0 += h0*wz[k];   ar0 += h0*wr[k];
            az1 += h1*wz[k+1]; ar1 += h1*wr[k+1];
            az2 += h2*wz[k+2]; ar2 += h2*wr[k+2];
            az3 += h3*wz[k+3]; ar3 += h3*wr[k+3];
        }
        float z = 1.f/(1.f + __expf(-((az0+az1)+(az2+az3))));
        float r = 1.f/(1.f + __expf(-((ar0+ar1)+(ar2+ar3))));
        float rh = r*h;

        // ht_j = lrelu(xh + sum_k rh[k] * Wh[128+k][j], 0.01)
        float ah0 = xh, ah1 = 0.f, ah2 = 0.f, ah3 = 0.f;
        #pragma unroll
        for(int k=0;k<64;k+=4){
            float r0 = rdlane(rh, k);
            float r1 = rdlane(rh, k+1);
            float r2 = rdlane(rh, k+2);
            float r3 = rdlane(rh, k+3);
            ah0 += r0*wh[k];
            ah1 += r1*wh[k+1];
            ah2 += r2*wh[k+2];
            ah3 += r3*wh[k+3];
        }
        float s2 = (ah0+ah1)+(ah2+ah3);
        float ht = (s2 > 0.f) ? s2 : 0.01f*s2;

        h = (1.f - z)*h + z*ht;
        xz = nxz; xr = nxr; xh = nxh;
    }
    out[(size_t)b*64 + j] = h;
}

extern "C" void kernel_launch(void* const* d_in, const int* in_sizes, int n_in,
                              void* d_out, int out_size, void* d_ws, size_t ws_size,
                              hipStream_t stream) {
    const float* x    = (const float*)d_in[0];
    const int*   nidx = (const int*)d_in[1];
    const int*   src  = (const int*)d_in[2];
    const int*   dst  = src + NE_;
    const float* emb  = (const float*)d_in[3];
    const float* W1 = (const float*)d_in[4];
    const float* a1s = (const float*)d_in[5];
    const float* a1d = (const float*)d_in[6];
    const float* b1 = (const float*)d_in[7];
    const float* W2 = (const float*)d_in[8];
    const float* a2s = (const float*)d_in[9];
    const float* a2d = (const float*)d_in[10];
    const float* b2 = (const float*)d_in[11];
    const float* W3 = (const float*)d_in[12];
    const float* a3s = (const float*)d_in[13];
    const float* a3d = (const float*)d_in[14];
    const float* b3 = (const float*)d_in[15];
    const float* fcW = (const float*)d_in[16];
    const float* fcb = (const float*)d_in[17];
    const float* Wz = (const float*)d_in[18];
    const float* bz = (const float*)d_in[19];
    const float* Wr = (const float*)d_in[20];
    const float* br = (const float*)d_in[21];
    const float* Wh = (const float*)d_in[22];
    const float* bh = (const float*)d_in[23];
    float* out = (float*)d_out;

    // ---- workspace layout: 128 MB total ----
    float* ws = (float*)d_ws;
    float* hAgg = ws;                          // NN*128
    float* X3   = hAgg + (size_t)NN_*128;      // NE*192
    float* bufA = X3;                          // NN*128   (alias)
    float* h64  = bufA + (size_t)NN_*128;      // NN*64    (alias)
    float* ssrc = h64  + (size_t)NN_*64;       // NN       (alias)
    float* sdst = ssrc + NN_;                  // NN
    float* ssum = sdst + NN_;                  // NN
    unsigned* menc = (unsigned*)(ssum + NN_);  // NN
    float* ebuf = (float*)menc + NN_;          // NE+NN

    const int EP = NE_ + NN_;                  // 196608 edges incl self-loops

    k_embed<<<NN_*64/256, 256, 0, stream>>>(x, nidx, emb, h64);

    const float* Ws[3]  = {W1, W2, W3};
    const float* as_[3] = {a1s, a2s, a3s};
    const float* ad_[3] = {a1d, a2d, a3d};
    const float* bs[3]  = {b1, b2, b3};

    for(int l=0; l<3; l++){
        // GEMM first (reads prev activations from hAgg for l>0), then zero hAgg
        if(l == 0)
            k_gemm_node<64><<<NN_/16, 256, 0, stream>>>(h64, Ws[l], bufA);
        else
            k_gemm_node<128><<<NN_/16, 256, 0, stream>>>(hAgg, Ws[l], bufA);
        k_zero<<<2048, 256, 0, stream>>>(hAgg, NN_*128);
        k_zero<<<512, 256, 0, stream>>>(ssum, 2*NN_);   // ssum + menc (contiguous)
        k_rowdots<<<NN_/4, 256, 0, stream>>>(bufA, as_[l], ad_[l], ssrc, sdst);
        k_edge1<<<EP/256, 256, 0, stream>>>(src, dst, ssrc, sdst, ebuf, menc);
        k_edge2<<<EP/256, 256, 0, stream>>>(dst, menc, ebuf, ssum);
        k_edge3<<<EP*32/256, 256, 0, stream>>>(src, dst, ebuf, ssum, bufA, hAgg);
        k_biasgelu<<<NN_*128/256, 256, 0, stream>>>(hAgg, bs[l]);
    }

    k_ef_x3<<<NE_/16, 256, 0, stream>>>(hAgg, src, dst, fcW, fcb,
                                        Wz, Wr, Wh, bz, br, bh, X3);
    k_gru<<<B_, 64, 0, stream>>>(X3, Wz, Wr, Wh, out);
}

// Round 5
// 5112.735 us; speedup vs baseline: 1.1046x; 1.1046x over previous
//
#include <hip/hip_runtime.h>
#include <hip/hip_bf16.h>
#include <math.h>

#define NN_ 65536
#define NE_ 131072
#define B_  32
#define T_  4096

__device__ __forceinline__ float gelu_f(float x){
    return 0.5f*x*(1.0f + erff(x*0.70710678118654752f));
}

// monotonic float<->uint encoding for atomicMax on floats
__device__ __forceinline__ unsigned enc_f(float f){
    unsigned b = __float_as_uint(f);
    return (b & 0x80000000u) ? ~b : (b | 0x80000000u);
}
__device__ __forceinline__ float dec_f(unsigned u){
    return (u & 0x80000000u) ? __uint_as_float(u ^ 0x80000000u) : __uint_as_float(~u);
}

// broadcast lane l's value of v to all lanes (compile-time l -> v_readlane)
__device__ __forceinline__ float rdlane(float v, int l){
    return __int_as_float(__builtin_amdgcn_readlane(__float_as_int(v), l));
}

// ---------------- zero ----------------
__global__ void k_zero(float* p, int n){
    int i = blockIdx.x*blockDim.x + threadIdx.x;
    int stride = gridDim.x*blockDim.x;
    for(; i<n; i+=stride) p[i] = 0.f;
}

// ---------------- embed concat: h64[n][c] = c<32 ? x[n][c] : emb[nidx[n]][c-32] ----
__global__ void k_embed(const float* __restrict__ x, const int* __restrict__ nidx,
                        const float* __restrict__ emb, float* __restrict__ h64){
    int gid = blockIdx.x*256 + threadIdx.x;
    int n = gid >> 6, c = gid & 63;
    float v = (c < 32) ? x[(size_t)n*32 + c] : emb[(size_t)nidx[n]*32 + (c-32)];
    h64[gid] = v;
}

// ---------------- node GEMM: C[M,128] = A[M,K] @ W[K,128] ----------------
template<int K>
__global__ void k_gemm_node(const float* __restrict__ A, const float* __restrict__ W,
                            float* __restrict__ C){
    int lane = threadIdx.x & 63;
    int wy = threadIdx.x >> 6;
    int r0 = blockIdx.x*16 + wy*4;
    const float* a0 = A + (size_t)r0*K;
    float acc0[4] = {0,0,0,0}, acc1[4] = {0,0,0,0};
    #pragma unroll 4
    for(int k=0;k<K;k+=4){
        float4 av[4];
        #pragma unroll
        for(int i=0;i<4;i++) av[i] = *(const float4*)(a0 + (size_t)i*K + k);
        #pragma unroll
        for(int kk=0;kk<4;kk++){
            float w0 = W[(size_t)(k+kk)*128 + lane];
            float w1 = W[(size_t)(k+kk)*128 + 64 + lane];
            #pragma unroll
            for(int i=0;i<4;i++){
                float a = ((const float*)&av[i])[kk];
                acc0[i] += a*w0;
                acc1[i] += a*w1;
            }
        }
    }
    #pragma unroll
    for(int i=0;i<4;i++){
        C[(size_t)(r0+i)*128 + lane]      = acc0[i];
        C[(size_t)(r0+i)*128 + 64 + lane] = acc1[i];
    }
}

// ---------------- per-row dots: ssrc = hW . a_s, sdst = hW . a_d --------------
__global__ void k_rowdots(const float* __restrict__ hW, const float* __restrict__ as_,
                          const float* __restrict__ ad_, float* __restrict__ ssrc,
                          float* __restrict__ sdst){
    int lane = threadIdx.x & 63;
    int row = blockIdx.x*4 + (threadIdx.x >> 6);
    const float* hp = hW + (size_t)row*128;
    float h0 = hp[lane], h1 = hp[lane+64];
    float d0 = h0*as_[lane] + h1*as_[lane+64];
    float d1 = h0*ad_[lane] + h1*ad_[lane+64];
    #pragma unroll
    for(int off=32; off; off>>=1){
        d0 += __shfl_xor(d0, off);
        d1 += __shfl_xor(d1, off);
    }
    if(lane==0){ ssrc[row] = d0; sdst[row] = d1; }
}

// ---------------- edge pass 1: e = lrelu(ssrc[s]+sdst[d]); max into m[d] ------
__global__ void k_edge1(const int* __restrict__ src, const int* __restrict__ dst,
                        const float* __restrict__ ssrc, const float* __restrict__ sdst,
                        float* __restrict__ ebuf, unsigned* __restrict__ menc){
    int e = blockIdx.x*256 + threadIdx.x;   // e < NE_+NN_
    int s, d;
    if(e < NE_){ s = src[e]; d = dst[e]; } else { s = d = e - NE_; }
    float v = ssrc[s] + sdst[d];
    v = (v > 0.f) ? v : 0.2f*v;
    ebuf[e] = v;
    atomicMax(&menc[d], enc_f(v));
}

// ---------------- edge pass 2: ex = exp(e - m[d]); sum into ssum[d] -----------
__global__ void k_edge2(const int* __restrict__ dst, const unsigned* __restrict__ menc,
                        float* __restrict__ ebuf, float* __restrict__ ssum){
    int e = blockIdx.x*256 + threadIdx.x;
    int d = (e < NE_) ? dst[e] : (e - NE_);
    float m = dec_f(menc[d]);
    float ex = __expf(ebuf[e] - m);
    ebuf[e] = ex;
    atomicAdd(&ssum[d], ex);
}

// ---------------- alpha: ebuf[e] = ex / ssum[d] -------------------------------
__global__ void k_alpha(const int* __restrict__ dst, const float* __restrict__ ssum,
                        float* __restrict__ ebuf){
    int e = blockIdx.x*256 + threadIdx.x;
    int d = (e < NE_) ? dst[e] : (e - NE_);
    ebuf[e] = ebuf[e] / ssum[d];
}

// ---------------- edge pass 3 (LDS-staged per graph) + bias + gelu ------------
// grid (32 graphs, 16 ch-groups); block 256. agg[2048][8] in LDS (64KB).
// hAgg[d][c] = gelu( sum_e alpha_e * hW[s_e][c] + bias[c] )
__global__ void __launch_bounds__(256) k_edge3_lds(
        const int* __restrict__ src, const int* __restrict__ dst,
        const float* __restrict__ ebuf, const float* __restrict__ hW,
        const float* __restrict__ bias, float* __restrict__ hAgg){
    __shared__ float agg[2048][8];
    int g  = blockIdx.x;
    int c0 = blockIdx.y << 3;
    int t  = threadIdx.x;
    int cc = t & 7;
    int elane = t >> 3;              // 0..31 (32 edges per iter)

    for(int idx = t; idx < 2048*8; idx += 256)
        ((float*)agg)[idx] = 0.f;
    __syncthreads();

    const int gbase_e = g << 12;     // g*4096 edges
    const int gbase_n = g << 11;     // g*2048 nodes
    for(int i = 0; i < 192; i++){
        int eg = i*32 + elane;       // 0..6143
        int s, dloc; float a;
        if(eg < 4096){
            int e = gbase_e + eg;
            s    = src[e];
            dloc = dst[e] - gbase_n;
            a    = ebuf[e];
        } else {
            int nl = eg - 4096;
            s    = gbase_n + nl;
            dloc = nl;
            a    = ebuf[NE_ + gbase_n + nl];
        }
        float v = hW[(size_t)s*128 + c0 + cc] * a;
        atomicAdd(&agg[dloc][cc], v);
    }
    __syncthreads();

    for(int idx = t; idx < 2048*8; idx += 256){
        int nl = idx >> 3;
        int ch = c0 + (idx & 7);
        hAgg[((size_t)(gbase_n + nl))*128 + ch] = gelu_f(agg[nl][idx & 7] + bias[ch]);
    }
}

// ------- fused edge-FC + GRU input projection:
//   efrow = gelu([h3[src[e]] | h3[dst[e]]] @ fcW + fcb)           [128]
//   X3[(t*32+b)*192 + {z|r|h}] = efrow @ {Wz,Wr,Wh}[0:128] + bias [64 each]
__global__ void k_ef_x3(const float* __restrict__ h3, const int* __restrict__ src,
                        const int* __restrict__ dst, const float* __restrict__ fcW,
                        const float* __restrict__ fcb,
                        const float* __restrict__ Wz, const float* __restrict__ Wr,
                        const float* __restrict__ Wh, const float* __restrict__ bz,
                        const float* __restrict__ br, const float* __restrict__ bh,
                        float* __restrict__ X3){
    __shared__ float efs[16][128];
    int lane = threadIdx.x & 63;
    int wy = threadIdx.x >> 6;
    int e0 = blockIdx.x*16 + wy*4;

    // phase 1: edge-FC
    {
        float acc0[4] = {0,0,0,0}, acc1[4] = {0,0,0,0};
        #pragma unroll
        for(int half=0; half<2; half++){
            const float* rowp[4];
            #pragma unroll
            for(int i=0;i<4;i++){
                int n = (half==0) ? src[e0+i] : dst[e0+i];
                rowp[i] = h3 + (size_t)n*128;
            }
            #pragma unroll 2
            for(int k=0;k<128;k+=4){
                float4 av[4];
                #pragma unroll
                for(int i=0;i<4;i++) av[i] = *(const float4*)(rowp[i] + k);
                #pragma unroll
                for(int kk=0;kk<4;kk++){
                    int kw = half*128 + k + kk;
                    float w0 = fcW[(size_t)kw*128 + lane];
                    float w1 = fcW[(size_t)kw*128 + 64 + lane];
                    #pragma unroll
                    for(int i=0;i<4;i++){
                        float a = ((const float*)&av[i])[kk];
                        acc0[i] += a*w0;
                        acc1[i] += a*w1;
                    }
                }
            }
        }
        float b0 = fcb[lane], b1 = fcb[64+lane];
        #pragma unroll
        for(int i=0;i<4;i++){
            efs[wy*4+i][lane]      = gelu_f(acc0[i] + b0);
            efs[wy*4+i][64 + lane] = gelu_f(acc1[i] + b1);
        }
    }
    __syncthreads();
    // phase 2: project to z/r/h inputs
    {
        float accz[4] = {0,0,0,0}, accr[4] = {0,0,0,0}, acch[4] = {0,0,0,0};
        #pragma unroll 2
        for(int k=0;k<128;k+=4){
            #pragma unroll
            for(int kk=0;kk<4;kk++){
                float w0 = Wz[(size_t)(k+kk)*64 + lane];
                float w1 = Wr[(size_t)(k+kk)*64 + lane];
                float w2 = Wh[(size_t)(k+kk)*64 + lane];
                #pragma unroll
                for(int i=0;i<4;i++){
                    float a = efs[wy*4+i][k+kk];
                    accz[i] += a*w0;
                    accr[i] += a*w1;
                    acch[i] += a*w2;
                }
            }
        }
        float b0 = bz[lane], b1 = br[lane], b2 = bh[lane];
        #pragma unroll
        for(int i=0;i<4;i++){
            int e = e0 + i;
            int bb = e >> 12;       // graph
            int t  = e & 4095;      // timestep
            float* o = X3 + ((size_t)t*32 + bb)*192;
            o[lane]       = accz[i] + b0;
            o[64 + lane]  = accr[i] + b1;
            o[128 + lane] = acch[i] + b2;
        }
    }
}

// ---------------- GRU: 1 wave per batch; weights in LDS (float2-interleaved) --
// lane j owns output j; hid distributed 1 elem/lane; broadcasts via v_readlane.
// WZR[k][j] = (Wz_h[k][j], Wr_h[k][j]) -> one ds_read_b64 feeds both gates.
// WH2[kk][j] = (Wh_h[2kk][j], Wh_h[2kk+1][j]). ~40 VGPRs, no AGPR spills.
__global__ void __launch_bounds__(64) k_gru(const float* __restrict__ X3,
                       const float* __restrict__ Wz, const float* __restrict__ Wr,
                       const float* __restrict__ Wh, float* __restrict__ out){
    __shared__ float2 WZR[64][64];
    __shared__ float2 WH2[32][64];
    int b = blockIdx.x;
    int j = threadIdx.x;        // 0..63

    for(int k=0;k<64;k++)
        WZR[k][j] = make_float2(Wz[(size_t)(128+k)*64 + j], Wr[(size_t)(128+k)*64 + j]);
    for(int kk=0;kk<32;kk++)
        WH2[kk][j] = make_float2(Wh[(size_t)(128+2*kk)*64 + j], Wh[(size_t)(128+2*kk+1)*64 + j]);
    __syncthreads();

    float h = 0.f;
    const float* x0 = X3 + (size_t)b*192;
    float xz = x0[j], xr = x0[64+j], xh = x0[128+j];

    for(int step=0; step<T_; step++){
        float nxz, nxr, nxh;
        if(step + 1 < T_){
            const float* np = X3 + ((size_t)(step+1)*32 + b)*192;
            nxz = np[j]; nxr = np[64+j]; nxh = np[128+j];
        } else { nxz = nxr = nxh = 0.f; }

        // z_j, r_j = sigmoid(x + sum_k hid[k] * W[128+k][j])
        float az0 = xz, az1 = 0.f, az2 = 0.f, az3 = 0.f;
        float ar0 = xr, ar1 = 0.f, ar2 = 0.f, ar3 = 0.f;
        #pragma unroll
        for(int k=0;k<64;k+=4){
            float2 w0 = WZR[k  ][j];
            float2 w1 = WZR[k+1][j];
            float2 w2 = WZR[k+2][j];
            float2 w3 = WZR[k+3][j];
            float h0 = rdlane(h, k);
            float h1 = rdlane(h, k+1);
            float h2 = rdlane(h, k+2);
            float h3 = rdlane(h, k+3);
            az0 += h0*w0.x; ar0 += h0*w0.y;
            az1 += h1*w1.x; ar1 += h1*w1.y;
            az2 += h2*w2.x; ar2 += h2*w2.y;
            az3 += h3*w3.x; ar3 += h3*w3.y;
        }
        float z = 1.f/(1.f + __expf(-((az0+az1)+(az2+az3))));
        float r = 1.f/(1.f + __expf(-((ar0+ar1)+(ar2+ar3))));
        float rh = r*h;

        // ht_j = lrelu(xh + sum_k rh[k] * Wh[128+k][j], 0.01)
        float ah0 = xh, ah1 = 0.f, ah2 = 0.f, ah3 = 0.f;
        #pragma unroll
        for(int kk=0;kk<32;kk+=2){
            float2 w0 = WH2[kk  ][j];
            float2 w1 = WH2[kk+1][j];
            float r0 = rdlane(rh, 2*kk);
            float r1 = rdlane(rh, 2*kk+1);
            float r2 = rdlane(rh, 2*kk+2);
            float r3 = rdlane(rh, 2*kk+3);
            ah0 += r0*w0.x;
            ah1 += r1*w0.y;
            ah2 += r2*w1.x;
            ah3 += r3*w1.y;
        }
        float s2 = (ah0+ah1)+(ah2+ah3);
        float ht = (s2 > 0.f) ? s2 : 0.01f*s2;

        h = (1.f - z)*h + z*ht;
        xz = nxz; xr = nxr; xh = nxh;
    }
    out[(size_t)b*64 + j] = h;
}

extern "C" void kernel_launch(void* const* d_in, const int* in_sizes, int n_in,
                              void* d_out, int out_size, void* d_ws, size_t ws_size,
                              hipStream_t stream) {
    const float* x    = (const float*)d_in[0];
    const int*   nidx = (const int*)d_in[1];
    const int*   src  = (const int*)d_in[2];
    const int*   dst  = src + NE_;
    const float* emb  = (const float*)d_in[3];
    const float* W1 = (const float*)d_in[4];
    const float* a1s = (const float*)d_in[5];
    const float* a1d = (const float*)d_in[6];
    const float* b1 = (const float*)d_in[7];
    const float* W2 = (const float*)d_in[8];
    const float* a2s = (const float*)d_in[9];
    const float* a2d = (const float*)d_in[10];
    const float* b2 = (const float*)d_in[11];
    const float* W3 = (const float*)d_in[12];
    const float* a3s = (const float*)d_in[13];
    const float* a3d = (const float*)d_in[14];
    const float* b3 = (const float*)d_in[15];
    const float* fcW = (const float*)d_in[16];
    const float* fcb = (const float*)d_in[17];
    const float* Wz = (const float*)d_in[18];
    const float* bz = (const float*)d_in[19];
    const float* Wr = (const float*)d_in[20];
    const float* br = (const float*)d_in[21];
    const float* Wh = (const float*)d_in[22];
    const float* bh = (const float*)d_in[23];
    float* out = (float*)d_out;

    // ---- workspace layout: 128 MB total ----
    float* ws = (float*)d_ws;
    float* hAgg = ws;                          // NN*128 (activations, fully written each layer)
    float* X3   = hAgg + (size_t)NN_*128;      // NE*192
    float* bufA = X3;                          // NN*128   (alias)
    float* h64  = bufA + (size_t)NN_*128;      // NN*64    (alias)
    float* ssrc = h64  + (size_t)NN_*64;       // NN       (alias)
    float* sdst = ssrc + NN_;                  // NN
    float* ssum = sdst + NN_;                  // NN
    unsigned* menc = (unsigned*)(ssum + NN_);  // NN
    float* ebuf = (float*)menc + NN_;          // NE+NN

    const int EP = NE_ + NN_;                  // 196608 edges incl self-loops

    k_embed<<<NN_*64/256, 256, 0, stream>>>(x, nidx, emb, h64);

    const float* Ws[3]  = {W1, W2, W3};
    const float* as_[3] = {a1s, a2s, a3s};
    const float* ad_[3] = {a1d, a2d, a3d};
    const float* bs[3]  = {b1, b2, b3};

    for(int l=0; l<3; l++){
        if(l == 0)
            k_gemm_node<64><<<NN_/16, 256, 0, stream>>>(h64, Ws[l], bufA);
        else
            k_gemm_node<128><<<NN_/16, 256, 0, stream>>>(hAgg, Ws[l], bufA);
        k_zero<<<512, 256, 0, stream>>>(ssum, 2*NN_);   // ssum + menc (contiguous)
        k_rowdots<<<NN_/4, 256, 0, stream>>>(bufA, as_[l], ad_[l], ssrc, sdst);
        k_edge1<<<EP/256, 256, 0, stream>>>(src, dst, ssrc, sdst, ebuf, menc);
        k_edge2<<<EP/256, 256, 0, stream>>>(dst, menc, ebuf, ssum);
        k_alpha<<<EP/256, 256, 0, stream>>>(dst, ssum, ebuf);
        k_edge3_lds<<<dim3(B_, 16), 256, 0, stream>>>(src, dst, ebuf, bufA, bs[l], hAgg);
    }

    k_ef_x3<<<NE_/16, 256, 0, stream>>>(hAgg, src, dst, fcW, fcb,
                                        Wz, Wr, Wh, bz, br, bh, X3);
    k_gru<<<B_, 64, 0, stream>>>(X3, Wz, Wr, Wh, out);
}

// Round 6
// 4384.784 us; speedup vs baseline: 1.2880x; 1.1660x over previous
//
#include <hip/hip_runtime.h>
#include <hip/hip_bf16.h>
#include <math.h>

#define NN_ 65536
#define NE_ 131072
#define B_  32
#define T_  4096

__device__ __forceinline__ float gelu_f(float x){
    return 0.5f*x*(1.0f + erff(x*0.70710678118654752f));
}

// monotonic float<->uint encoding for atomicMax on floats
__device__ __forceinline__ unsigned enc_f(float f){
    unsigned b = __float_as_uint(f);
    return (b & 0x80000000u) ? ~b : (b | 0x80000000u);
}
__device__ __forceinline__ float dec_f(unsigned u){
    return (u & 0x80000000u) ? __uint_as_float(u ^ 0x80000000u) : __uint_as_float(~u);
}

// broadcast lane l's value of v to all lanes (compile-time l -> v_readlane)
__device__ __forceinline__ float rdlane(float v, int l){
    return __int_as_float(__builtin_amdgcn_readlane(__float_as_int(v), l));
}

// pin 8 consecutive array elements into VGPRs (defeats AGPR-home heuristic)
#define PIN8(A,I) asm volatile("" : "+v"(A[I]),"+v"(A[(I)+1]),"+v"(A[(I)+2]),"+v"(A[(I)+3]), \
                                     "+v"(A[(I)+4]),"+v"(A[(I)+5]),"+v"(A[(I)+6]),"+v"(A[(I)+7]))
#define PIN64(A) PIN8(A,0); PIN8(A,8); PIN8(A,16); PIN8(A,24); PIN8(A,32); PIN8(A,40); PIN8(A,48); PIN8(A,56)

// ---------------- zero ----------------
__global__ void k_zero(float* p, int n){
    int i = blockIdx.x*blockDim.x + threadIdx.x;
    int stride = gridDim.x*blockDim.x;
    for(; i<n; i+=stride) p[i] = 0.f;
}

// ---------------- embed concat: h64[n][c] = c<32 ? x[n][c] : emb[nidx[n]][c-32] ----
__global__ void k_embed(const float* __restrict__ x, const int* __restrict__ nidx,
                        const float* __restrict__ emb, float* __restrict__ h64){
    int gid = blockIdx.x*256 + threadIdx.x;
    int n = gid >> 6, c = gid & 63;
    float v = (c < 32) ? x[(size_t)n*32 + c] : emb[(size_t)nidx[n]*32 + (c-32)];
    h64[gid] = v;
}

// ---------------- node GEMM: C[M,128] = A[M,K] @ W[K,128] ----------------
template<int K>
__global__ void k_gemm_node(const float* __restrict__ A, const float* __restrict__ W,
                            float* __restrict__ C){
    int lane = threadIdx.x & 63;
    int wy = threadIdx.x >> 6;
    int r0 = blockIdx.x*16 + wy*4;
    const float* a0 = A + (size_t)r0*K;
    float acc0[4] = {0,0,0,0}, acc1[4] = {0,0,0,0};
    #pragma unroll 4
    for(int k=0;k<K;k+=4){
        float4 av[4];
        #pragma unroll
        for(int i=0;i<4;i++) av[i] = *(const float4*)(a0 + (size_t)i*K + k);
        #pragma unroll
        for(int kk=0;kk<4;kk++){
            float w0 = W[(size_t)(k+kk)*128 + lane];
            float w1 = W[(size_t)(k+kk)*128 + 64 + lane];
            #pragma unroll
            for(int i=0;i<4;i++){
                float a = ((const float*)&av[i])[kk];
                acc0[i] += a*w0;
                acc1[i] += a*w1;
            }
        }
    }
    #pragma unroll
    for(int i=0;i<4;i++){
        C[(size_t)(r0+i)*128 + lane]      = acc0[i];
        C[(size_t)(r0+i)*128 + 64 + lane] = acc1[i];
    }
}

// ---------------- per-row dots: ssrc = hW . a_s, sdst = hW . a_d --------------
__global__ void k_rowdots(const float* __restrict__ hW, const float* __restrict__ as_,
                          const float* __restrict__ ad_, float* __restrict__ ssrc,
                          float* __restrict__ sdst){
    int lane = threadIdx.x & 63;
    int row = blockIdx.x*4 + (threadIdx.x >> 6);
    const float* hp = hW + (size_t)row*128;
    float h0 = hp[lane], h1 = hp[lane+64];
    float d0 = h0*as_[lane] + h1*as_[lane+64];
    float d1 = h0*ad_[lane] + h1*ad_[lane+64];
    #pragma unroll
    for(int off=32; off; off>>=1){
        d0 += __shfl_xor(d0, off);
        d1 += __shfl_xor(d1, off);
    }
    if(lane==0){ ssrc[row] = d0; sdst[row] = d1; }
}

// ---------------- edge pass 1: e = lrelu(ssrc[s]+sdst[d]); max into m[d] ------
__global__ void k_edge1(const int* __restrict__ src, const int* __restrict__ dst,
                        const float* __restrict__ ssrc, const float* __restrict__ sdst,
                        float* __restrict__ ebuf, unsigned* __restrict__ menc){
    int e = blockIdx.x*256 + threadIdx.x;   // e < NE_+NN_
    int s, d;
    if(e < NE_){ s = src[e]; d = dst[e]; } else { s = d = e - NE_; }
    float v = ssrc[s] + sdst[d];
    v = (v > 0.f) ? v : 0.2f*v;
    ebuf[e] = v;
    atomicMax(&menc[d], enc_f(v));
}

// ---------------- edge pass 2: ex = exp(e - m[d]); sum into ssum[d] -----------
__global__ void k_edge2(const int* __restrict__ dst, const unsigned* __restrict__ menc,
                        float* __restrict__ ebuf, float* __restrict__ ssum){
    int e = blockIdx.x*256 + threadIdx.x;
    int d = (e < NE_) ? dst[e] : (e - NE_);
    float m = dec_f(menc[d]);
    float ex = __expf(ebuf[e] - m);
    ebuf[e] = ex;
    atomicAdd(&ssum[d], ex);
}

// ---------------- alpha: ebuf[e] = ex / ssum[d] -------------------------------
__global__ void k_alpha(const int* __restrict__ dst, const float* __restrict__ ssum,
                        float* __restrict__ ebuf){
    int e = blockIdx.x*256 + threadIdx.x;
    int d = (e < NE_) ? dst[e] : (e - NE_);
    ebuf[e] = ebuf[e] / ssum[d];
}

// ---------------- edge pass 3 (LDS-staged per graph) + bias + gelu ------------
// grid (32 graphs, 16 ch-groups); block 256. agg[2048][8] in LDS (64KB).
// hAgg[d][c] = gelu( sum_e alpha_e * hW[s_e][c] + bias[c] )
__global__ void __launch_bounds__(256) k_edge3_lds(
        const int* __restrict__ src, const int* __restrict__ dst,
        const float* __restrict__ ebuf, const float* __restrict__ hW,
        const float* __restrict__ bias, float* __restrict__ hAgg){
    __shared__ float agg[2048][8];
    int g  = blockIdx.x;
    int c0 = blockIdx.y << 3;
    int t  = threadIdx.x;
    int cc = t & 7;
    int elane = t >> 3;              // 0..31 (32 edges per iter)

    for(int idx = t; idx < 2048*8; idx += 256)
        ((float*)agg)[idx] = 0.f;
    __syncthreads();

    const int gbase_e = g << 12;     // g*4096 edges
    const int gbase_n = g << 11;     // g*2048 nodes
    for(int i = 0; i < 192; i++){
        int eg = i*32 + elane;       // 0..6143
        int s, dloc; float a;
        if(eg < 4096){
            int e = gbase_e + eg;
            s    = src[e];
            dloc = dst[e] - gbase_n;
            a    = ebuf[e];
        } else {
            int nl = eg - 4096;
            s    = gbase_n + nl;
            dloc = nl;
            a    = ebuf[NE_ + gbase_n + nl];
        }
        float v = hW[(size_t)s*128 + c0 + cc] * a;
        atomicAdd(&agg[dloc][cc], v);
    }
    __syncthreads();

    for(int idx = t; idx < 2048*8; idx += 256){
        int nl = idx >> 3;
        int ch = c0 + (idx & 7);
        hAgg[((size_t)(gbase_n + nl))*128 + ch] = gelu_f(agg[nl][idx & 7] + bias[ch]);
    }
}

// ------- fused edge-FC + GRU input projection:
//   efrow = gelu([h3[src[e]] | h3[dst[e]]] @ fcW + fcb)           [128]
//   X3[(t*32+b)*192 + {z|r|h}] = efrow @ {Wz,Wr,Wh}[0:128] + bias [64 each]
__global__ void k_ef_x3(const float* __restrict__ h3, const int* __restrict__ src,
                        const int* __restrict__ dst, const float* __restrict__ fcW,
                        const float* __restrict__ fcb,
                        const float* __restrict__ Wz, const float* __restrict__ Wr,
                        const float* __restrict__ Wh, const float* __restrict__ bz,
                        const float* __restrict__ br, const float* __restrict__ bh,
                        float* __restrict__ X3){
    __shared__ float efs[16][128];
    int lane = threadIdx.x & 63;
    int wy = threadIdx.x >> 6;
    int e0 = blockIdx.x*16 + wy*4;

    // phase 1: edge-FC
    {
        float acc0[4] = {0,0,0,0}, acc1[4] = {0,0,0,0};
        #pragma unroll
        for(int half=0; half<2; half++){
            const float* rowp[4];
            #pragma unroll
            for(int i=0;i<4;i++){
                int n = (half==0) ? src[e0+i] : dst[e0+i];
                rowp[i] = h3 + (size_t)n*128;
            }
            #pragma unroll 2
            for(int k=0;k<128;k+=4){
                float4 av[4];
                #pragma unroll
                for(int i=0;i<4;i++) av[i] = *(const float4*)(rowp[i] + k);
                #pragma unroll
                for(int kk=0;kk<4;kk++){
                    int kw = half*128 + k + kk;
                    float w0 = fcW[(size_t)kw*128 + lane];
                    float w1 = fcW[(size_t)kw*128 + 64 + lane];
                    #pragma unroll
                    for(int i=0;i<4;i++){
                        float a = ((const float*)&av[i])[kk];
                        acc0[i] += a*w0;
                        acc1[i] += a*w1;
                    }
                }
            }
        }
        float b0 = fcb[lane], b1 = fcb[64+lane];
        #pragma unroll
        for(int i=0;i<4;i++){
            efs[wy*4+i][lane]      = gelu_f(acc0[i] + b0);
            efs[wy*4+i][64 + lane] = gelu_f(acc1[i] + b1);
        }
    }
    __syncthreads();
    // phase 2: project to z/r/h inputs
    {
        float accz[4] = {0,0,0,0}, accr[4] = {0,0,0,0}, acch[4] = {0,0,0,0};
        #pragma unroll 2
        for(int k=0;k<128;k+=4){
            #pragma unroll
            for(int kk=0;kk<4;kk++){
                float w0 = Wz[(size_t)(k+kk)*64 + lane];
                float w1 = Wr[(size_t)(k+kk)*64 + lane];
                float w2 = Wh[(size_t)(k+kk)*64 + lane];
                #pragma unroll
                for(int i=0;i<4;i++){
                    float a = efs[wy*4+i][k+kk];
                    accz[i] += a*w0;
                    accr[i] += a*w1;
                    acch[i] += a*w2;
                }
            }
        }
        float b0 = bz[lane], b1 = br[lane], b2 = bh[lane];
        #pragma unroll
        for(int i=0;i<4;i++){
            int e = e0 + i;
            int bb = e >> 12;       // graph
            int t  = e & 4095;      // timestep
            float* o = X3 + ((size_t)t*32 + bb)*192;
            o[lane]       = accz[i] + b0;
            o[64 + lane]  = accr[i] + b1;
            o[128 + lane] = acch[i] + b2;
        }
    }
}

// ---------------- GRU: 1 wave per batch, all-register recurrence --------------
// lane j owns output j. hid distributed 1 elem/lane; broadcasts via v_readlane
// (compile-time lane index). Weight columns held in VGPRs — the in-loop PIN64
// asm makes an AGPR/scratch home strictly worse, forcing true VGPR residency
// (R3/R4 showed the allocator otherwise parks them in AGPRs: VGPR_Count=108).
__global__ void __launch_bounds__(64) k_gru(const float* __restrict__ X3,
                       const float* __restrict__ Wz, const float* __restrict__ Wr,
                       const float* __restrict__ Wh, float* __restrict__ out){
    int b = blockIdx.x;
    int j = threadIdx.x;        // 0..63

    // hidden-part weight columns (rows 128..191, col j)
    float wz[64], wr[64], wh[64];
    #pragma unroll
    for(int k=0;k<64;k++){
        wz[k] = Wz[(size_t)(128+k)*64 + j];
        wr[k] = Wr[(size_t)(128+k)*64 + j];
        wh[k] = Wh[(size_t)(128+k)*64 + j];
    }

    float h = 0.f;
    const float* x0 = X3 + (size_t)b*192;
    float xz = x0[j], xr = x0[64+j], xh = x0[128+j];

    for(int step=0; step<T_; step++){
        PIN64(wz); PIN64(wr); PIN64(wh);   // keep weights in VGPRs every iter

        float nxz, nxr, nxh;
        if(step + 1 < T_){
            const float* np = X3 + ((size_t)(step+1)*32 + b)*192;
            nxz = np[j]; nxr = np[64+j]; nxh = np[128+j];
        } else { nxz = nxr = nxh = 0.f; }

        // z_j, r_j = sigmoid(x + sum_k hid[k] * W[128+k][j])
        float az0 = xz, az1 = 0.f, az2 = 0.f, az3 = 0.f;
        float ar0 = xr, ar1 = 0.f, ar2 = 0.f, ar3 = 0.f;
        #pragma unroll
        for(int k=0;k<64;k+=4){
            float h0 = rdlane(h, k);
            float h1 = rdlane(h, k+1);
            float h2 = rdlane(h, k+2);
            float h3 = rdlane(h, k+3);
            az0 += h0*wz[k];   ar0 += h0*wr[k];
            az1 += h1*wz[k+1]; ar1 += h1*wr[k+1];
            az2 += h2*wz[k+2]; ar2 += h2*wr[k+2];
            az3 += h3*wz[k+3]; ar3 += h3*wr[k+3];
        }
        float z = 1.f/(1.f + __expf(-((az0+az1)+(az2+az3))));
        float r = 1.f/(1.f + __expf(-((ar0+ar1)+(ar2+ar3))));
        float rh = r*h;

        // ht_j = lrelu(xh + sum_k rh[k] * Wh[128+k][j], 0.01)
        float ah0 = xh, ah1 = 0.f, ah2 = 0.f, ah3 = 0.f;
        #pragma unroll
        for(int k=0;k<64;k+=4){
            float r0 = rdlane(rh, k);
            float r1 = rdlane(rh, k+1);
            float r2 = rdlane(rh, k+2);
            float r3 = rdlane(rh, k+3);
            ah0 += r0*wh[k];
            ah1 += r1*wh[k+1];
            ah2 += r2*wh[k+2];
            ah3 += r3*wh[k+3];
        }
        float s2 = (ah0+ah1)+(ah2+ah3);
        float ht = (s2 > 0.f) ? s2 : 0.01f*s2;

        h = (1.f - z)*h + z*ht;
        xz = nxz; xr = nxr; xh = nxh;
    }
    out[(size_t)b*64 + j] = h;
}

extern "C" void kernel_launch(void* const* d_in, const int* in_sizes, int n_in,
                              void* d_out, int out_size, void* d_ws, size_t ws_size,
                              hipStream_t stream) {
    const float* x    = (const float*)d_in[0];
    const int*   nidx = (const int*)d_in[1];
    const int*   src  = (const int*)d_in[2];
    const int*   dst  = src + NE_;
    const float* emb  = (const float*)d_in[3];
    const float* W1 = (const float*)d_in[4];
    const float* a1s = (const float*)d_in[5];
    const float* a1d = (const float*)d_in[6];
    const float* b1 = (const float*)d_in[7];
    const float* W2 = (const float*)d_in[8];
    const float* a2s = (const float*)d_in[9];
    const float* a2d = (const float*)d_in[10];
    const float* b2 = (const float*)d_in[11];
    const float* W3 = (const float*)d_in[12];
    const float* a3s = (const float*)d_in[13];
    const float* a3d = (const float*)d_in[14];
    const float* b3 = (const float*)d_in[15];
    const float* fcW = (const float*)d_in[16];
    const float* fcb = (const float*)d_in[17];
    const float* Wz = (const float*)d_in[18];
    const float* bz = (const float*)d_in[19];
    const float* Wr = (const float*)d_in[20];
    const float* br = (const float*)d_in[21];
    const float* Wh = (const float*)d_in[22];
    const float* bh = (const float*)d_in[23];
    float* out = (float*)d_out;

    // ---- workspace layout: 128 MB total ----
    float* ws = (float*)d_ws;
    float* hAgg = ws;                          // NN*128 (activations, fully written each layer)
    float* X3   = hAgg + (size_t)NN_*128;      // NE*192
    float* bufA = X3;                          // NN*128   (alias)
    float* h64  = bufA + (size_t)NN_*128;      // NN*64    (alias)
    float* ssrc = h64  + (size_t)NN_*64;       // NN       (alias)
    float* sdst = ssrc + NN_;                  // NN
    float* ssum = sdst + NN_;                  // NN
    unsigned* menc = (unsigned*)(ssum + NN_);  // NN
    float* ebuf = (float*)menc + NN_;          // NE+NN

    const int EP = NE_ + NN_;                  // 196608 edges incl self-loops

    k_embed<<<NN_*64/256, 256, 0, stream>>>(x, nidx, emb, h64);

    const float* Ws[3]  = {W1, W2, W3};
    const float* as_[3] = {a1s, a2s, a3s};
    const float* ad_[3] = {a1d, a2d, a3d};
    const float* bs[3]  = {b1, b2, b3};

    for(int l=0; l<3; l++){
        if(l == 0)
            k_gemm_node<64><<<NN_/16, 256, 0, stream>>>(h64, Ws[l], bufA);
        else
            k_gemm_node<128><<<NN_/16, 256, 0, stream>>>(hAgg, Ws[l], bufA);
        k_zero<<<512, 256, 0, stream>>>(ssum, 2*NN_);   // ssum + menc (contiguous)
        k_rowdots<<<NN_/4, 256, 0, stream>>>(bufA, as_[l], ad_[l], ssrc, sdst);
        k_edge1<<<EP/256, 256, 0, stream>>>(src, dst, ssrc, sdst, ebuf, menc);
        k_edge2<<<EP/256, 256, 0, stream>>>(dst, menc, ebuf, ssum);
        k_alpha<<<EP/256, 256, 0, stream>>>(dst, ssum, ebuf);
        k_edge3_lds<<<dim3(B_, 16), 256, 0, stream>>>(src, dst, ebuf, bufA, bs[l], hAgg);
    }

    k_ef_x3<<<NE_/16, 256, 0, stream>>>(hAgg, src, dst, fcW, fcb,
                                        Wz, Wr, Wh, bz, br, bh, X3);
    k_gru<<<B_, 64, 0, stream>>>(X3, Wz, Wr, Wh, out);
}

// Round 7
// 3768.192 us; speedup vs baseline: 1.4988x; 1.1636x over previous
//
#include <hip/hip_runtime.h>
#include <hip/hip_bf16.h>
#include <math.h>

#define NN_ 65536
#define NE_ 131072
#define B_  32
#define T_  4096

__device__ __forceinline__ float gelu_f(float x){
    return 0.5f*x*(1.0f + erff(x*0.70710678118654752f));
}

// monotonic float<->uint encoding for atomicMax on floats
__device__ __forceinline__ unsigned enc_f(float f){
    unsigned b = __float_as_uint(f);
    return (b & 0x80000000u) ? ~b : (b | 0x80000000u);
}
__device__ __forceinline__ float dec_f(unsigned u){
    return (u & 0x80000000u) ? __uint_as_float(u ^ 0x80000000u) : __uint_as_float(~u);
}

// broadcast lane l's value of v to all lanes (l wave-uniform -> v_readlane)
__device__ __forceinline__ float rdlane(float v, int l){
    return __int_as_float(__builtin_amdgcn_readlane(__float_as_int(v), l));
}

// ---------------- zero ----------------
__global__ void k_zero(float* p, int n){
    int i = blockIdx.x*blockDim.x + threadIdx.x;
    int stride = gridDim.x*blockDim.x;
    for(; i<n; i+=stride) p[i] = 0.f;
}

// ---------------- embed concat: h64[n][c] = c<32 ? x[n][c] : emb[nidx[n]][c-32] ----
__global__ void k_embed(const float* __restrict__ x, const int* __restrict__ nidx,
                        const float* __restrict__ emb, float* __restrict__ h64){
    int gid = blockIdx.x*256 + threadIdx.x;
    int n = gid >> 6, c = gid & 63;
    float v = (c < 32) ? x[(size_t)n*32 + c] : emb[(size_t)nidx[n]*32 + (c-32)];
    h64[gid] = v;
}

// ---------------- node GEMM: C[M,128] = A[M,K] @ W[K,128] ----------------
template<int K>
__global__ void k_gemm_node(const float* __restrict__ A, const float* __restrict__ W,
                            float* __restrict__ C){
    int lane = threadIdx.x & 63;
    int wy = threadIdx.x >> 6;
    int r0 = blockIdx.x*16 + wy*4;
    const float* a0 = A + (size_t)r0*K;
    float acc0[4] = {0,0,0,0}, acc1[4] = {0,0,0,0};
    #pragma unroll 4
    for(int k=0;k<K;k+=4){
        float4 av[4];
        #pragma unroll
        for(int i=0;i<4;i++) av[i] = *(const float4*)(a0 + (size_t)i*K + k);
        #pragma unroll
        for(int kk=0;kk<4;kk++){
            float w0 = W[(size_t)(k+kk)*128 + lane];
            float w1 = W[(size_t)(k+kk)*128 + 64 + lane];
            #pragma unroll
            for(int i=0;i<4;i++){
                float a = ((const float*)&av[i])[kk];
                acc0[i] += a*w0;
                acc1[i] += a*w1;
            }
        }
    }
    #pragma unroll
    for(int i=0;i<4;i++){
        C[(size_t)(r0+i)*128 + lane]      = acc0[i];
        C[(size_t)(r0+i)*128 + 64 + lane] = acc1[i];
    }
}

// ---------------- per-row dots: ssrc = hW . a_s, sdst = hW . a_d --------------
__global__ void k_rowdots(const float* __restrict__ hW, const float* __restrict__ as_,
                          const float* __restrict__ ad_, float* __restrict__ ssrc,
                          float* __restrict__ sdst){
    int lane = threadIdx.x & 63;
    int row = blockIdx.x*4 + (threadIdx.x >> 6);
    const float* hp = hW + (size_t)row*128;
    float h0 = hp[lane], h1 = hp[lane+64];
    float d0 = h0*as_[lane] + h1*as_[lane+64];
    float d1 = h0*ad_[lane] + h1*ad_[lane+64];
    #pragma unroll
    for(int off=32; off; off>>=1){
        d0 += __shfl_xor(d0, off);
        d1 += __shfl_xor(d1, off);
    }
    if(lane==0){ ssrc[row] = d0; sdst[row] = d1; }
}

// ---------------- edge pass 1: e = lrelu(ssrc[s]+sdst[d]); max into m[d] ------
__global__ void k_edge1(const int* __restrict__ src, const int* __restrict__ dst,
                        const float* __restrict__ ssrc, const float* __restrict__ sdst,
                        float* __restrict__ ebuf, unsigned* __restrict__ menc){
    int e = blockIdx.x*256 + threadIdx.x;   // e < NE_+NN_
    int s, d;
    if(e < NE_){ s = src[e]; d = dst[e]; } else { s = d = e - NE_; }
    float v = ssrc[s] + sdst[d];
    v = (v > 0.f) ? v : 0.2f*v;
    ebuf[e] = v;
    atomicMax(&menc[d], enc_f(v));
}

// ---------------- edge pass 2: ex = exp(e - m[d]); sum into ssum[d] -----------
__global__ void k_edge2(const int* __restrict__ dst, const unsigned* __restrict__ menc,
                        float* __restrict__ ebuf, float* __restrict__ ssum){
    int e = blockIdx.x*256 + threadIdx.x;
    int d = (e < NE_) ? dst[e] : (e - NE_);
    float m = dec_f(menc[d]);
    float ex = __expf(ebuf[e] - m);
    ebuf[e] = ex;
    atomicAdd(&ssum[d], ex);
}

// ---------------- edge pass 3 (LDS-staged per graph) + alpha + bias + gelu ----
// grid (32 graphs, 16 ch-groups); block 256. agg[2048][8] in LDS (64KB).
// hAgg[d][c] = gelu( sum_e (ex_e/ssum[d]) * hW[s_e][c] + bias[c] )
__global__ void __launch_bounds__(256) k_edge3_lds(
        const int* __restrict__ src, const int* __restrict__ dst,
        const float* __restrict__ ebuf, const float* __restrict__ ssum,
        const float* __restrict__ hW, const float* __restrict__ bias,
        float* __restrict__ hAgg){
    __shared__ float agg[2048][8];
    int g  = blockIdx.x;
    int c0 = blockIdx.y << 3;
    int t  = threadIdx.x;
    int cc = t & 7;
    int elane = t >> 3;              // 0..31 (32 edges per iter)

    for(int idx = t; idx < 2048*8; idx += 256)
        ((float*)agg)[idx] = 0.f;
    __syncthreads();

    const int gbase_e = g << 12;     // g*4096 edges
    const int gbase_n = g << 11;     // g*2048 nodes
    for(int i = 0; i < 192; i++){
        int eg = i*32 + elane;       // 0..6143
        int s, dloc; float a;
        if(eg < 4096){
            int e = gbase_e + eg;
            s    = src[e];
            int d = dst[e];
            dloc = d - gbase_n;
            a    = ebuf[e] / ssum[d];
        } else {
            int nl = eg - 4096;
            s    = gbase_n + nl;
            dloc = nl;
            a    = ebuf[NE_ + gbase_n + nl] / ssum[gbase_n + nl];
        }
        float v = hW[(size_t)s*128 + c0 + cc] * a;
        atomicAdd(&agg[dloc][cc], v);
    }
    __syncthreads();

    for(int idx = t; idx < 2048*8; idx += 256){
        int nl = idx >> 3;
        int ch = c0 + (idx & 7);
        hAgg[((size_t)(gbase_n + nl))*128 + ch] = gelu_f(agg[nl][idx & 7] + bias[ch]);
    }
}

// ------- fused edge-FC + GRU input projection:
//   efrow = gelu([h3[src[e]] | h3[dst[e]]] @ fcW + fcb)           [128]
//   X3[(t*32+b)*192 + {z|r|h}] = efrow @ {Wz,Wr,Wh}[0:128] + bias [64 each]
__global__ void k_ef_x3(const float* __restrict__ h3, const int* __restrict__ src,
                        const int* __restrict__ dst, const float* __restrict__ fcW,
                        const float* __restrict__ fcb,
                        const float* __restrict__ Wz, const float* __restrict__ Wr,
                        const float* __restrict__ Wh, const float* __restrict__ bz,
                        const float* __restrict__ br, const float* __restrict__ bh,
                        float* __restrict__ X3){
    __shared__ float efs[16][128];
    int lane = threadIdx.x & 63;
    int wy = threadIdx.x >> 6;
    int e0 = blockIdx.x*16 + wy*4;

    // phase 1: edge-FC
    {
        float acc0[4] = {0,0,0,0}, acc1[4] = {0,0,0,0};
        #pragma unroll
        for(int half=0; half<2; half++){
            const float* rowp[4];
            #pragma unroll
            for(int i=0;i<4;i++){
                int n = (half==0) ? src[e0+i] : dst[e0+i];
                rowp[i] = h3 + (size_t)n*128;
            }
            #pragma unroll 2
            for(int k=0;k<128;k+=4){
                float4 av[4];
                #pragma unroll
                for(int i=0;i<4;i++) av[i] = *(const float4*)(rowp[i] + k);
                #pragma unroll
                for(int kk=0;kk<4;kk++){
                    int kw = half*128 + k + kk;
                    float w0 = fcW[(size_t)kw*128 + lane];
                    float w1 = fcW[(size_t)kw*128 + 64 + lane];
                    #pragma unroll
                    for(int i=0;i<4;i++){
                        float a = ((const float*)&av[i])[kk];
                        acc0[i] += a*w0;
                        acc1[i] += a*w1;
                    }
                }
            }
        }
        float b0 = fcb[lane], b1 = fcb[64+lane];
        #pragma unroll
        for(int i=0;i<4;i++){
            efs[wy*4+i][lane]      = gelu_f(acc0[i] + b0);
            efs[wy*4+i][64 + lane] = gelu_f(acc1[i] + b1);
        }
    }
    __syncthreads();
    // phase 2: project to z/r/h inputs
    {
        float accz[4] = {0,0,0,0}, accr[4] = {0,0,0,0}, acch[4] = {0,0,0,0};
        #pragma unroll 2
        for(int k=0;k<128;k+=4){
            #pragma unroll
            for(int kk=0;kk<4;kk++){
                float w0 = Wz[(size_t)(k+kk)*64 + lane];
                float w1 = Wr[(size_t)(k+kk)*64 + lane];
                float w2 = Wh[(size_t)(k+kk)*64 + lane];
                #pragma unroll
                for(int i=0;i<4;i++){
                    float a = efs[wy*4+i][k+kk];
                    accz[i] += a*w0;
                    accr[i] += a*w1;
                    acch[i] += a*w2;
                }
            }
        }
        float b0 = bz[lane], b1 = br[lane], b2 = bh[lane];
        #pragma unroll
        for(int i=0;i<4;i++){
            int e = e0 + i;
            int bb = e >> 12;       // graph
            int t  = e & 4095;      // timestep
            float* o = X3 + ((size_t)t*32 + bb)*192;
            o[lane]       = accz[i] + b0;
            o[64 + lane]  = accr[i] + b1;
            o[128 + lane] = acch[i] + b2;
        }
    }
}

// ---------------- GRU: 4 waves per batch, k-split matvec partials -------------
// Wave w owns k in [16w,16w+16): only 48 weight floats/lane -> true VGPR
// residency (R3-R6 showed a single wave's 192 floats get AGPR-parked at the
// ~108-reg cap). h replicated in all waves (identical redundant update from
// shared partial sums); per-wave broadcasts via v_readlane; two tiny LDS
// exchanges + 2 barriers per step combine the k-partials.
__global__ void __launch_bounds__(256) k_gru(const float* __restrict__ X3,
                       const float* __restrict__ Wz, const float* __restrict__ Wr,
                       const float* __restrict__ Wh, float* __restrict__ out){
    __shared__ float2 P1[4][64];
    __shared__ float  P2[4][64];
    int b = blockIdx.x;
    int j = threadIdx.x & 63;
    int w = __builtin_amdgcn_readfirstlane(threadIdx.x >> 6);  // wave id 0..3
    int kbase = w << 4;

    // hidden-part weight columns: rows 128+kbase .. 128+kbase+15, col j
    float wz[16], wr[16], wh[16];
    #pragma unroll
    for(int i=0;i<16;i++){
        wz[i] = Wz[(size_t)(128+kbase+i)*64 + j];
        wr[i] = Wr[(size_t)(128+kbase+i)*64 + j];
        wh[i] = Wh[(size_t)(128+kbase+i)*64 + j];
    }

    float h = 0.f;
    const float* x0 = X3 + (size_t)b*192;
    float xz = x0[j], xr = x0[64+j], xh = x0[128+j];

    for(int step=0; step<T_; step++){
        float nxz, nxr, nxh;
        if(step + 1 < T_){
            const float* np = X3 + ((size_t)(step+1)*32 + b)*192;
            nxz = np[j]; nxr = np[64+j]; nxh = np[128+j];
        } else { nxz = nxr = nxh = 0.f; }

        // phase 1: partial z/r matvec over this wave's k-range
        float az0=0.f, az1=0.f, ar0=0.f, ar1=0.f;
        #pragma unroll
        for(int i=0;i<16;i+=2){
            float h0 = rdlane(h, kbase+i);
            float h1 = rdlane(h, kbase+i+1);
            az0 = fmaf(h0, wz[i],   az0); ar0 = fmaf(h0, wr[i],   ar0);
            az1 = fmaf(h1, wz[i+1], az1); ar1 = fmaf(h1, wr[i+1], ar1);
        }
        P1[w][j] = make_float2(az0+az1, ar0+ar1);
        __syncthreads();
        float2 p0 = P1[0][j], p1 = P1[1][j], p2 = P1[2][j], p3 = P1[3][j];
        float sz = xz + ((p0.x+p1.x)+(p2.x+p3.x));
        float sr = xr + ((p0.y+p1.y)+(p2.y+p3.y));
        float z = 1.f/(1.f + __expf(-sz));
        float r = 1.f/(1.f + __expf(-sr));
        float rh = r*h;

        // phase 2: partial ht matvec over this wave's k-range
        float ah0=0.f, ah1=0.f;
        #pragma unroll
        for(int i=0;i<16;i+=2){
            float r0 = rdlane(rh, kbase+i);
            float r1 = rdlane(rh, kbase+i+1);
            ah0 = fmaf(r0, wh[i],   ah0);
            ah1 = fmaf(r1, wh[i+1], ah1);
        }
        P2[w][j] = ah0+ah1;
        __syncthreads();
        float s2 = xh + ((P2[0][j]+P2[1][j]) + (P2[2][j]+P2[3][j]));
        float ht = (s2 > 0.f) ? s2 : 0.01f*s2;

        h = (1.f - z)*h + z*ht;   // identical in all waves -> h stays replicated
        xz = nxz; xr = nxr; xh = nxh;
    }
    if(w == 0) out[(size_t)b*64 + j] = h;
}

extern "C" void kernel_launch(void* const* d_in, const int* in_sizes, int n_in,
                              void* d_out, int out_size, void* d_ws, size_t ws_size,
                              hipStream_t stream) {
    const float* x    = (const float*)d_in[0];
    const int*   nidx = (const int*)d_in[1];
    const int*   src  = (const int*)d_in[2];
    const int*   dst  = src + NE_;
    const float* emb  = (const float*)d_in[3];
    const float* W1 = (const float*)d_in[4];
    const float* a1s = (const float*)d_in[5];
    const float* a1d = (const float*)d_in[6];
    const float* b1 = (const float*)d_in[7];
    const float* W2 = (const float*)d_in[8];
    const float* a2s = (const float*)d_in[9];
    const float* a2d = (const float*)d_in[10];
    const float* b2 = (const float*)d_in[11];
    const float* W3 = (const float*)d_in[12];
    const float* a3s = (const float*)d_in[13];
    const float* a3d = (const float*)d_in[14];
    const float* b3 = (const float*)d_in[15];
    const float* fcW = (const float*)d_in[16];
    const float* fcb = (const float*)d_in[17];
    const float* Wz = (const float*)d_in[18];
    const float* bz = (const float*)d_in[19];
    const float* Wr = (const float*)d_in[20];
    const float* br = (const float*)d_in[21];
    const float* Wh = (const float*)d_in[22];
    const float* bh = (const float*)d_in[23];
    float* out = (float*)d_out;

    // ---- workspace layout: 128 MB total ----
    float* ws = (float*)d_ws;
    float* hAgg = ws;                          // NN*128 (activations, fully written each layer)
    float* X3   = hAgg + (size_t)NN_*128;      // NE*192
    float* bufA = X3;                          // NN*128   (alias)
    float* h64  = bufA + (size_t)NN_*128;      // NN*64    (alias)
    float* ssrc = h64  + (size_t)NN_*64;       // NN       (alias)
    float* sdst = ssrc + NN_;                  // NN
    float* ssum = sdst + NN_;                  // NN
    unsigned* menc = (unsigned*)(ssum + NN_);  // NN
    float* ebuf = (float*)menc + NN_;          // NE+NN

    const int EP = NE_ + NN_;                  // 196608 edges incl self-loops

    k_embed<<<NN_*64/256, 256, 0, stream>>>(x, nidx, emb, h64);

    const float* Ws[3]  = {W1, W2, W3};
    const float* as_[3] = {a1s, a2s, a3s};
    const float* ad_[3] = {a1d, a2d, a3d};
    const float* bs[3]  = {b1, b2, b3};

    for(int l=0; l<3; l++){
        if(l == 0)
            k_gemm_node<64><<<NN_/16, 256, 0, stream>>>(h64, Ws[l], bufA);
        else
            k_gemm_node<128><<<NN_/16, 256, 0, stream>>>(hAgg, Ws[l], bufA);
        k_zero<<<512, 256, 0, stream>>>(ssum, 2*NN_);   // ssum + menc (contiguous)
        k_rowdots<<<NN_/4, 256, 0, stream>>>(bufA, as_[l], ad_[l], ssrc, sdst);
        k_edge1<<<EP/256, 256, 0, stream>>>(src, dst, ssrc, sdst, ebuf, menc);
        k_edge2<<<EP/256, 256, 0, stream>>>(dst, menc, ebuf, ssum);
        k_edge3_lds<<<dim3(B_, 16), 256, 0, stream>>>(src, dst, ebuf, ssum, bufA, bs[l], hAgg);
    }

    k_ef_x3<<<NE_/16, 256, 0, stream>>>(hAgg, src, dst, fcW, fcb,
                                        Wz, Wr, Wh, bz, br, bh, X3);
    k_gru<<<B_, 256, 0, stream>>>(X3, Wz, Wr, Wh, out);
}